// Round 13
// baseline (126.314 us; speedup 1.0000x reference)
//
#include <hip/hip_runtime.h>
#include <stdint.h>

#define BATCH   8
#define CDIM    32
#define KLBL    64
#define NPB     200000               // n per batch (6250 * 32)
#define SLABS   6250                 // 32-n slabs per batch
#define CHUNKS  128                  // 128*8 = 1024 blocks = 4 per CU
#define REC     (KLBL * CDIM + KLBL)

typedef __attribute__((ext_vector_type(8))) short bf16x8;
typedef __attribute__((ext_vector_type(4))) float f32x4;

union ABits { uint32_t u[4]; bf16x8 v; };

__device__ __forceinline__ uint32_t cvtpk_bf16(float lo, float hi) {
  uint32_t r;
  asm volatile("v_cvt_pk_bf16_f32 %0, %1, %2" : "=v"(r) : "v"(lo), "v"(hi));
  return r;
}
__device__ __forceinline__ float agent_ld(const float* p) {
  return __hip_atomic_load(p, __ATOMIC_RELAXED, __HIP_MEMORY_SCOPE_AGENT);
}

// ---------------- fused: one-hot MFMA segment sums + per-batch loss tail --
// grid = (CHUNKS, BATCH), block = 256 (4 waves), 4 blocks/CU -> 16 waves/CU.
// Core loop identical to R12 (verified): derive(consume regs) -> prefetch
// load -> sched_barrier -> MFMA. After the global-atomic flush, the last
// block of each batch (per-batch completion counter, R9-validated fence/
// agent-scope pattern) computes that batch's hinge loss -> atomicAdd(out).
__global__ __launch_bounds__(256, 4) void seg_mfma_kernel(
    const float* __restrict__ pred,     // [B][C][N] f32
    const int*   __restrict__ label,    // [B][N] i32
    float* __restrict__ gsums,          // [B][K][C] pre-zeroed
    float* __restrict__ gcounts,        // [B][K]    pre-zeroed
    uint32_t* __restrict__ counters,    // [B]       pre-zeroed
    float* __restrict__ out) {          // scalar    pre-zeroed (memset)
  __shared__ float s_part[4][REC];      // 33.8KB flush buffer (reused by tail)
  __shared__ uint32_t s_last;

  const int tid = threadIdx.x;
  const int wv = tid >> 6;
  const int ln = tid & 63;
  const int chunk = blockIdx.x, b = blockIdx.y;

  const int s0 = (int)((long long)chunk * SLABS / CHUNKS);
  const int s1 = (int)((long long)(chunk + 1) * SLABS / CHUNKS);
  const int w0 = s0 + (int)((long long)(s1 - s0) * wv / 4);
  const int w1 = s0 + (int)((long long)(s1 - s0) * (wv + 1) / 4);

  const int crow = ln & 15;          // channel row (and A label-row)
  const int g    = ln >> 4;          // 8-n sub-group within slab
  const int kseg = g * 8;

  const float* row0 = pred + ((size_t)b * CDIM + crow) * NPB;       // c-lo
  const float* row1 = pred + ((size_t)b * CDIM + crow + 16) * NPB;  // c-hi
  const int*   labp = label + (size_t)b * NPB;

  f32x4 acc[4][2];   // [k-tile][c-tile], compile-time indices only
#pragma unroll
  for (int kt = 0; kt < 4; ++kt) {
    acc[kt][0] = (f32x4){0.f, 0.f, 0.f, 0.f};
    acc[kt][1] = (f32x4){0.f, 0.f, 0.f, 0.f};
  }
  uint32_t cnt0 = 0, cnt1 = 0, cnt2 = 0, cnt3 = 0;

  // two named prefetch register sets (depth-2, static names only)
  float4 fA0, fA1, fA2, fA3;  int4 lA0, lA1;   // even slabs
  float4 fB0, fB1, fB2, fB3;  int4 lB0, lB1;   // odd slabs

  auto loadA = [&](int s) {
    const int n0 = s * 32 + kseg;
    fA0 = *(const float4*)(row0 + n0);
    fA1 = *(const float4*)(row0 + n0 + 4);
    fA2 = *(const float4*)(row1 + n0);
    fA3 = *(const float4*)(row1 + n0 + 4);
    lA0 = *(const int4*)(labp + n0);
    lA1 = *(const int4*)(labp + n0 + 4);
  };
  auto loadB = [&](int s) {
    const int n0 = s * 32 + kseg;
    fB0 = *(const float4*)(row0 + n0);
    fB1 = *(const float4*)(row0 + n0 + 4);
    fB2 = *(const float4*)(row1 + n0);
    fB3 = *(const float4*)(row1 + n0 + 4);
    lB0 = *(const int4*)(labp + n0);
    lB1 = *(const int4*)(labp + n0 + 4);
  };

  ABits b0v, b1v, av[4];   // derived per slab (av indexed by unrolled kt only)

  // derive CONSUMES the f*/l* registers completely (safe to overwrite after)
  auto derive = [&](const float4& f0, const float4& f1, const float4& f2,
                    const float4& f3, const int4& l0, const int4& l1) {
    b0v.u[0] = cvtpk_bf16(f0.x, f0.y);
    b0v.u[1] = cvtpk_bf16(f0.z, f0.w);
    b0v.u[2] = cvtpk_bf16(f1.x, f1.y);
    b0v.u[3] = cvtpk_bf16(f1.z, f1.w);
    b1v.u[0] = cvtpk_bf16(f2.x, f2.y);
    b1v.u[1] = cvtpk_bf16(f2.z, f2.w);
    b1v.u[2] = cvtpk_bf16(f3.x, f3.y);
    b1v.u[3] = cvtpk_bf16(f3.z, f3.w);
#pragma unroll
    for (int kt = 0; kt < 4; ++kt) {
      const int tgt = kt * 16 + crow;
      av[kt].u[0] = (l0.x == tgt ? 0x3F80u : 0u) | (l0.y == tgt ? 0x3F800000u : 0u);
      av[kt].u[1] = (l0.z == tgt ? 0x3F80u : 0u) | (l0.w == tgt ? 0x3F800000u : 0u);
      av[kt].u[2] = (l1.x == tgt ? 0x3F80u : 0u) | (l1.y == tgt ? 0x3F800000u : 0u);
      av[kt].u[3] = (l1.z == tgt ? 0x3F80u : 0u) | (l1.w == tgt ? 0x3F800000u : 0u);
      const uint32_t m =
          (uint32_t)(l0.x == tgt) + (uint32_t)(l0.y == tgt) +
          (uint32_t)(l0.z == tgt) + (uint32_t)(l0.w == tgt) +
          (uint32_t)(l1.x == tgt) + (uint32_t)(l1.y == tgt) +
          (uint32_t)(l1.z == tgt) + (uint32_t)(l1.w == tgt);
      if (kt == 0) cnt0 += m; else if (kt == 1) cnt1 += m;
      else if (kt == 2) cnt2 += m; else cnt3 += m;
    }
  };

  auto mfma_step = [&]() {
#pragma unroll
    for (int kt = 0; kt < 4; ++kt) {
      acc[kt][0] = __builtin_amdgcn_mfma_f32_16x16x32_bf16(av[kt].v, b0v.v, acc[kt][0], 0, 0, 0);
      acc[kt][1] = __builtin_amdgcn_mfma_f32_16x16x32_bf16(av[kt].v, b1v.v, acc[kt][1], 0, 0, 0);
    }
  };

  // ---- prologue ----
  if (w0 < w1) loadA(w0);
  if (w0 + 1 < w1) loadB(w0 + 1);

  // ---- main loop: derive(consume) -> prefetch load -> MFMA (R12-verified) --
  int s = w0;
  while (s < w1) {
    derive(fA0, fA1, fA2, fA3, lA0, lA1);    // consumes A-set fully
    if (s + 2 < w1) loadA(s + 2);            // now safe to overwrite A-set
    __builtin_amdgcn_sched_barrier(0);       // keep loads above the MFMAs
    mfma_step();
    ++s;
    if (s >= w1) break;
    derive(fB0, fB1, fB2, fB3, lB0, lB1);
    if (s + 2 < w1) loadB(s + 2);
    __builtin_amdgcn_sched_barrier(0);
    mfma_step();
    ++s;
  }

  // ---- flush: 4-wave LDS reduce, then global atomics (R12-verified) ----
  s_part[wv][KLBL * CDIM + ln] = 0.f;
#pragma unroll
  for (int kt = 0; kt < 4; ++kt) {
#pragma unroll
    for (int r = 0; r < 4; ++r) {
      const int k = kt * 16 + g * 4 + r;     // D: col=ln&15, row=(ln>>4)*4+r
      s_part[wv][k * CDIM + crow]      = acc[kt][0][r];
      s_part[wv][k * CDIM + 16 + crow] = acc[kt][1][r];
    }
  }
  atomicAdd(&s_part[wv][KLBL * CDIM + 0 * 16 + crow], (float)cnt0);
  atomicAdd(&s_part[wv][KLBL * CDIM + 1 * 16 + crow], (float)cnt1);
  atomicAdd(&s_part[wv][KLBL * CDIM + 2 * 16 + crow], (float)cnt2);
  atomicAdd(&s_part[wv][KLBL * CDIM + 3 * 16 + crow], (float)cnt3);
  __syncthreads();

  float* gs = gsums + (size_t)b * KLBL * CDIM;
  for (int i = tid; i < REC; i += 256) {
    const float v = s_part[0][i] + s_part[1][i] + s_part[2][i] + s_part[3][i];
    if (i < KLBL * CDIM) atomicAdd(&gs[i], v);
    else                 atomicAdd(&gcounts[b * KLBL + (i - KLBL * CDIM)], v);
  }

  // ---- per-batch completion: last block of batch b computes its loss ----
  __syncthreads();
  if (tid == 0) {
    __threadfence();   // make this block's atomics device-visible
    s_last = (__hip_atomic_fetch_add(&counters[b], 1u, __ATOMIC_ACQ_REL,
                                     __HIP_MEMORY_SCOPE_AGENT) == CHUNKS - 1);
  }
  __syncthreads();
  if (!s_last) return;
  __threadfence();

  float* cen = &s_part[0][0];        // 2048 floats (reuse flush LDS)
  float* red = cen + 2048;           // 256
  float* cb  = red + 256;            // 64
  if (tid < 64) cb[tid] = fmaxf(agent_ld(gcounts + b * 64 + tid), 1.0f);
  __syncthreads();
  for (int i = tid; i < 2048; i += 256)
    cen[i] = agent_ld(gsums + (size_t)b * 2048 + i) / cb[i >> 5];
  __syncthreads();

  float a2 = 0.f;
  for (int p = tid; p < 1024; p += 256) {
    const int i = p >> 5, j = p & 31;
    float gr = 0.f, ni = 0.f, nj = 0.f;
#pragma unroll
    for (int k = 0; k < KLBL; ++k) {
      const float ci = cen[k * 32 + i];
      const float cj = cen[k * 32 + j];
      gr += ci * cj;
      ni += ci * ci;
      nj += cj * cj;
    }
    float sq = fmaxf(ni + nj - 2.f * gr, 0.f);
    const float dist = (sq > 0.f) ? sqrtf(sq) : 0.f;
    const float h = fmaxf(3.0f - dist, 0.f);   // 2*D_DIST = 3.0
    a2 += h * h;
  }
  red[tid] = a2;
  __syncthreads();
  for (int s2 = 128; s2 > 0; s2 >>= 1) {
    if (tid < s2) red[tid] += red[tid + s2];
    __syncthreads();
  }
  if (tid == 0)
    atomicAdd(out, red[0] / (2.0f * (float)KLBL * ((float)KLBL - 1.0f)));
}

// ---------------- launch: 2 memsets + 1 kernel ----------------
extern "C" void kernel_launch(void* const* d_in, const int* in_sizes, int n_in,
                              void* d_out, int out_size, void* d_ws, size_t ws_size,
                              hipStream_t stream) {
  const float* pred  = (const float*)d_in[0];
  const int*   label = (const int*)d_in[1];

  float*    gsums    = (float*)d_ws;                          // B*K*C
  float*    gcounts  = gsums + (size_t)BATCH * KLBL * CDIM;   // B*K
  uint32_t* counters = (uint32_t*)(gcounts + BATCH * KLBL);   // B

  const size_t zero_bytes =
      (size_t)(BATCH * KLBL * CDIM + BATCH * KLBL + BATCH) * 4;
  hipMemsetAsync(d_ws, 0, zero_bytes, stream);
  hipMemsetAsync(d_out, 0, sizeof(float), stream);

  dim3 grid1(CHUNKS, BATCH);
  seg_mfma_kernel<<<grid1, 256, 0, stream>>>(pred, label, gsums, gcounts,
                                             counters, (float*)d_out);
}

// Round 14
// 59.703 us; speedup vs baseline: 2.1157x; 2.1157x over previous
//
#include <hip/hip_runtime.h>
#include <stdint.h>

#define BATCH   8
#define CDIM    32
#define KLBL    64
#define NPB     200000               // n per batch (6250 * 32)
#define SLABS   6250                 // 32-n slabs per batch
#define CHUNKS  128                  // 128*8 = 1024 blocks = 4 per CU
#define REC     (KLBL * CDIM + KLBL) // 2112 floats per wave-partial record

typedef __attribute__((ext_vector_type(8))) short bf16x8;
typedef __attribute__((ext_vector_type(4))) float f32x4;

union ABits { uint32_t u[4]; bf16x8 v; };

__device__ __forceinline__ uint32_t cvtpk_bf16(float lo, float hi) {
  uint32_t r;
  asm volatile("v_cvt_pk_bf16_f32 %0, %1, %2" : "=v"(r) : "v"(lo), "v"(hi));
  return r;
}

// ---------------- Kernel 1: barrier-free one-hot MFMA segment sums --------
// grid = (CHUNKS, BATCH), block = 256 (4 waves), 4 blocks/CU via
// __launch_bounds__(256,4) -> 16 waves/CU. Each WAVE owns an exclusive
// n-range; 8 MFMA per 32-n slab. Counts via integer popcount.
// Loop order (R12-verified): derive CONSUMES the prefetch registers into
// b0v/b1v/av FIRST, then the s+2 load may overwrite them, then MFMAs.
// NOTE (R13 lesson): do NOT fuse epilogue work into this kernel — extra
// code perturbs regalloc (VGPR 128->64) and serializes the prefetch loads.
__global__ __launch_bounds__(256, 4) void seg_mfma_kernel(
    const float* __restrict__ pred,     // [B][C][N] f32
    const int*   __restrict__ label,    // [B][N] i32
    float* __restrict__ gsums,          // [B][K][C] pre-zeroed
    float* __restrict__ gcounts,        // [B][K]    pre-zeroed
    float* __restrict__ out) {          // scalar; zeroed by block (0,0)
  __shared__ float s_part[4][REC];      // 33.8KB flush buffer

  const int tid = threadIdx.x;
  const int wv = tid >> 6;
  const int ln = tid & 63;
  const int chunk = blockIdx.x, b = blockIdx.y;

  if (chunk == 0 && b == 0 && tid == 0) out[0] = 0.f;  // loss runs after seg

  const int s0 = (int)((long long)chunk * SLABS / CHUNKS);
  const int s1 = (int)((long long)(chunk + 1) * SLABS / CHUNKS);
  const int w0 = s0 + (int)((long long)(s1 - s0) * wv / 4);
  const int w1 = s0 + (int)((long long)(s1 - s0) * (wv + 1) / 4);

  const int crow = ln & 15;          // channel row (and A label-row)
  const int g    = ln >> 4;          // 8-n sub-group within slab
  const int kseg = g * 8;

  const float* row0 = pred + ((size_t)b * CDIM + crow) * NPB;       // c-lo
  const float* row1 = pred + ((size_t)b * CDIM + crow + 16) * NPB;  // c-hi
  const int*   labp = label + (size_t)b * NPB;

  f32x4 acc[4][2];   // [k-tile][c-tile], compile-time indices only
#pragma unroll
  for (int kt = 0; kt < 4; ++kt) {
    acc[kt][0] = (f32x4){0.f, 0.f, 0.f, 0.f};
    acc[kt][1] = (f32x4){0.f, 0.f, 0.f, 0.f};
  }
  uint32_t cnt0 = 0, cnt1 = 0, cnt2 = 0, cnt3 = 0;  // label-count per k-tile

  // two named prefetch register sets (depth-2, static names only)
  float4 fA0, fA1, fA2, fA3;  int4 lA0, lA1;   // even slabs
  float4 fB0, fB1, fB2, fB3;  int4 lB0, lB1;   // odd slabs

  auto loadA = [&](int s) {
    const int n0 = s * 32 + kseg;
    fA0 = *(const float4*)(row0 + n0);
    fA1 = *(const float4*)(row0 + n0 + 4);
    fA2 = *(const float4*)(row1 + n0);
    fA3 = *(const float4*)(row1 + n0 + 4);
    lA0 = *(const int4*)(labp + n0);
    lA1 = *(const int4*)(labp + n0 + 4);
  };
  auto loadB = [&](int s) {
    const int n0 = s * 32 + kseg;
    fB0 = *(const float4*)(row0 + n0);
    fB1 = *(const float4*)(row0 + n0 + 4);
    fB2 = *(const float4*)(row1 + n0);
    fB3 = *(const float4*)(row1 + n0 + 4);
    lB0 = *(const int4*)(labp + n0);
    lB1 = *(const int4*)(labp + n0 + 4);
  };

  ABits b0v, b1v, av[4];   // derived per slab (av indexed by unrolled kt only)

  // derive CONSUMES the f*/l* registers completely (safe to overwrite after)
  auto derive = [&](const float4& f0, const float4& f1, const float4& f2,
                    const float4& f3, const int4& l0, const int4& l1) {
    b0v.u[0] = cvtpk_bf16(f0.x, f0.y);
    b0v.u[1] = cvtpk_bf16(f0.z, f0.w);
    b0v.u[2] = cvtpk_bf16(f1.x, f1.y);
    b0v.u[3] = cvtpk_bf16(f1.z, f1.w);
    b1v.u[0] = cvtpk_bf16(f2.x, f2.y);
    b1v.u[1] = cvtpk_bf16(f2.z, f2.w);
    b1v.u[2] = cvtpk_bf16(f3.x, f3.y);
    b1v.u[3] = cvtpk_bf16(f3.z, f3.w);
#pragma unroll
    for (int kt = 0; kt < 4; ++kt) {
      const int tgt = kt * 16 + crow;
      av[kt].u[0] = (l0.x == tgt ? 0x3F80u : 0u) | (l0.y == tgt ? 0x3F800000u : 0u);
      av[kt].u[1] = (l0.z == tgt ? 0x3F80u : 0u) | (l0.w == tgt ? 0x3F800000u : 0u);
      av[kt].u[2] = (l1.x == tgt ? 0x3F80u : 0u) | (l1.y == tgt ? 0x3F800000u : 0u);
      av[kt].u[3] = (l1.z == tgt ? 0x3F80u : 0u) | (l1.w == tgt ? 0x3F800000u : 0u);
      const uint32_t m =
          (uint32_t)(l0.x == tgt) + (uint32_t)(l0.y == tgt) +
          (uint32_t)(l0.z == tgt) + (uint32_t)(l0.w == tgt) +
          (uint32_t)(l1.x == tgt) + (uint32_t)(l1.y == tgt) +
          (uint32_t)(l1.z == tgt) + (uint32_t)(l1.w == tgt);
      if (kt == 0) cnt0 += m; else if (kt == 1) cnt1 += m;
      else if (kt == 2) cnt2 += m; else cnt3 += m;
    }
  };

  auto mfma_step = [&]() {
#pragma unroll
    for (int kt = 0; kt < 4; ++kt) {
      acc[kt][0] = __builtin_amdgcn_mfma_f32_16x16x32_bf16(av[kt].v, b0v.v, acc[kt][0], 0, 0, 0);
      acc[kt][1] = __builtin_amdgcn_mfma_f32_16x16x32_bf16(av[kt].v, b1v.v, acc[kt][1], 0, 0, 0);
    }
  };

  // ---- prologue ----
  if (w0 < w1) loadA(w0);
  if (w0 + 1 < w1) loadB(w0 + 1);

  // ---- main loop: derive(consume) -> prefetch load -> MFMA ----
  int s = w0;
  while (s < w1) {
    derive(fA0, fA1, fA2, fA3, lA0, lA1);    // consumes A-set fully
    if (s + 2 < w1) loadA(s + 2);            // now safe to overwrite A-set
    __builtin_amdgcn_sched_barrier(0);       // keep loads above the MFMAs
    mfma_step();
    ++s;
    if (s >= w1) break;
    derive(fB0, fB1, fB2, fB3, lB0, lB1);
    if (s + 2 < w1) loadB(s + 2);
    __builtin_amdgcn_sched_barrier(0);
    mfma_step();
    ++s;
  }

  // ---- flush: 4-wave LDS reduce, then global atomics ----
  // D mapping (m89-verified): col = ln&15, row = (ln>>4)*4 + r
  s_part[wv][KLBL * CDIM + ln] = 0.f;   // zero count region (wave-ordered)
#pragma unroll
  for (int kt = 0; kt < 4; ++kt) {
#pragma unroll
    for (int r = 0; r < 4; ++r) {
      const int k = kt * 16 + g * 4 + r;
      s_part[wv][k * CDIM + crow]      = acc[kt][0][r];
      s_part[wv][k * CDIM + 16 + crow] = acc[kt][1][r];
    }
  }
  // counts: lane (crow,g) holds count of label kt*16+crow among its n's
  atomicAdd(&s_part[wv][KLBL * CDIM + 0 * 16 + crow], (float)cnt0);
  atomicAdd(&s_part[wv][KLBL * CDIM + 1 * 16 + crow], (float)cnt1);
  atomicAdd(&s_part[wv][KLBL * CDIM + 2 * 16 + crow], (float)cnt2);
  atomicAdd(&s_part[wv][KLBL * CDIM + 3 * 16 + crow], (float)cnt3);
  __syncthreads();

  float* gs = gsums + (size_t)b * KLBL * CDIM;
  for (int i = tid; i < REC; i += 256) {
    const float v = s_part[0][i] + s_part[1][i] + s_part[2][i] + s_part[3][i];
    if (i < KLBL * CDIM) atomicAdd(&gs[i], v);
    else                 atomicAdd(&gcounts[b * KLBL + (i - KLBL * CDIM)], v);
  }
}

// ---------------- Kernel 2: centers -> pairwise hinge loss ----------------
__global__ __launch_bounds__(256) void loss_kernel(
    const float* __restrict__ gsums,    // [B][K][C]
    const float* __restrict__ gcounts,  // [B][K]
    float* __restrict__ out) {          // zeroed by seg block (0,0)
  const int b = blockIdx.x;
  __shared__ float s_center[KLBL * CDIM];
  __shared__ float s_red[256];

  for (int i = threadIdx.x; i < KLBL * CDIM; i += 256) {
    const float cnt = fmaxf(gcounts[b * KLBL + (i >> 5)], 1.0f);
    s_center[i] = gsums[(size_t)b * KLBL * CDIM + i] / cnt;
  }
  __syncthreads();

  float acc = 0.f;
  for (int p = threadIdx.x; p < CDIM * CDIM; p += 256) {
    const int i = p >> 5, j = p & 31;
    float gr = 0.f, ni = 0.f, nj = 0.f;
#pragma unroll
    for (int k = 0; k < KLBL; ++k) {
      const float ci = s_center[k * CDIM + i];
      const float cj = s_center[k * CDIM + j];
      gr += ci * cj;
      ni += ci * ci;
      nj += cj * cj;
    }
    float sq = fmaxf(ni + nj - 2.f * gr, 0.f);
    const float dist = (sq > 0.f) ? sqrtf(sq) : 0.f;
    const float h = fmaxf(3.0f - dist, 0.f);   // 2*D_DIST = 3.0
    acc += h * h;
  }

  s_red[threadIdx.x] = acc;
  __syncthreads();
  for (int s = 128; s > 0; s >>= 1) {
    if (threadIdx.x < s) s_red[threadIdx.x] += s_red[threadIdx.x + s];
    __syncthreads();
  }
  if (threadIdx.x == 0)
    atomicAdd(out, s_red[0] / (2.0f * (float)KLBL * ((float)KLBL - 1.0f)));
}

// ---------------- launch: 1 memset + 2 kernels ----------------
extern "C" void kernel_launch(void* const* d_in, const int* in_sizes, int n_in,
                              void* d_out, int out_size, void* d_ws, size_t ws_size,
                              hipStream_t stream) {
  const float* pred  = (const float*)d_in[0];
  const int*   label = (const int*)d_in[1];
  float* out = (float*)d_out;

  float* gsums   = (float*)d_ws;                        // B*K*C
  float* gcounts = gsums + (size_t)BATCH * KLBL * CDIM; // B*K

  const size_t accum_bytes =
      (size_t)(BATCH * KLBL * CDIM + BATCH * KLBL) * sizeof(float);
  hipMemsetAsync(d_ws, 0, accum_bytes, stream);

  dim3 grid1(CHUNKS, BATCH);
  seg_mfma_kernel<<<grid1, 256, 0, stream>>>(pred, label, gsums, gcounts, out);
  loss_kernel<<<BATCH, 256, 0, stream>>>(gsums, gcounts, out);
}